// Round 9
// baseline (9561.407 us; speedup 1.0000x reference)
//
#include <hip/hip_runtime.h>
#include <cstdint>
#include <cstddef>

// Problem constants (match reference)
#define NIT    500
#define GAMMA_ 5.0f
#define CC_    1e-3f
#define KAPPA_ 2.0627128075074256f
#define PEN_   100.0f
#define LR_    0.01f

// d_ws layout: pbuf [128 b][2 dir][2 parity][100] f32 = 204800 B, then flags [256] int
#define PBUF_BYTES (128*2*2*100*4)
#define FLAG_COUNT 256

__device__ __forceinline__ float rdlane(float v, int lane) {
  return __int_as_float(__builtin_amdgcn_readlane(__float_as_int(v), lane));
}

// Wave64 sum via DPP (row_shr 1,2,4,8 ; row_bcast15 ; row_bcast31), total in lane 63.
// Numerics verified r5/r7/r8.
__device__ __forceinline__ float wred64(float x) {
  int t;
  t = __builtin_amdgcn_update_dpp(0, __float_as_int(x), 0x111, 0xf, 0xf, true); x += __int_as_float(t);
  t = __builtin_amdgcn_update_dpp(0, __float_as_int(x), 0x112, 0xf, 0xf, true); x += __int_as_float(t);
  t = __builtin_amdgcn_update_dpp(0, __float_as_int(x), 0x114, 0xf, 0xf, true); x += __int_as_float(t);
  t = __builtin_amdgcn_update_dpp(0, __float_as_int(x), 0x118, 0xf, 0xf, true); x += __int_as_float(t);
  t = __builtin_amdgcn_update_dpp(0, __float_as_int(x), 0x142, 0xa, 0xf, true); x += __int_as_float(t);
  t = __builtin_amdgcn_update_dpp(0, __float_as_int(x), 0x143, 0xc, 0xf, true); x += __int_as_float(t);
  return rdlane(x, 63);
}

// r5 skeleton (256 WGs, one per (b,half), 6 heads x 2 waves, 2 barriers/iter) with
// two instruction-count cuts on the serial chain:
//  - matvec w-broadcast via wave-uniform ds_read_b128 (no v_readlane, no SGPR hazards)
//  - warm-started Michelot (r8-verified numerics, ~2 passes typical vs ~6)
__global__ __launch_bounds__(768, 1) void mpo_solver(
    const float* __restrict__ mu, const float* __restrict__ L,
    const float* __restrict__ wprev, const float* __restrict__ climit,
    float* __restrict__ out, float* __restrict__ pbuf, int* __restrict__ flags)
{
  const int tid  = threadIdx.x;
  const int lane = tid & 63;
  const int wave = __builtin_amdgcn_readfirstlane(tid >> 6);  // 0..11
  const int j    = wave >> 1;       // local head 0..5
  const int sec  = wave & 1;        // 0 = rows 0-49 + post, 1 = rows 50-99
  const int bid  = blockIdx.x;
  const int b    = bid & 127;
  const int half = bid >> 7;        // 0: heads 0-5, 1: heads 6-11
  const int h    = half * 6 + j;    // global head
  const int bh   = b * 12 + h;

  __shared__ float wbuf[2][6][100];   // double-buffered w per head
  __shared__ float ybuf[6][100];      // y = S w per head

  const float* Lb = L + (size_t)bh * 10000;

  // ---------- Phase 0: SYRK. Lane owns row r of S = L L^T (fp32, in registers). ----------
  float S[100];
#pragma unroll
  for (int c = 0; c < 100; ++c) S[c] = 0.f;
  const int r = sec * 50 + lane;      // valid row iff lane < 50
  if (lane < 50) {
#pragma unroll 1
    for (int mc = 0; mc < 25; ++mc) {
      float4 lr = *(const float4*)(Lb + r * 100 + mc * 4);
#pragma unroll
      for (int c = 0; c < 100; ++c) {
        const float* Lc = Lb + c * 100 + mc * 4;   // wave-uniform address -> scalar loads
        S[c] = fmaf(lr.x, Lc[0], fmaf(lr.y, Lc[1], fmaf(lr.z, Lc[2], fmaf(lr.w, Lc[3], S[c]))));
      }
    }
  }

  const bool val1 = (lane < 36);
  float mu0 = mu[(size_t)bh * 100 + lane];
  float mu1 = val1 ? mu[(size_t)bh * 100 + 64 + lane] : 0.f;
  float wp0 = wprev[b * 100 + lane];
  float wp1 = val1 ? wprev[b * 100 + 64 + lane] : 0.f;
  float lim = climit[b];

  float w0 = wp0, w1 = wp1;           // post wave's iterate (n = lane, 64+lane)

  if (sec == 0) {
    wbuf[0][j][lane] = wp0;
    if (val1) wbuf[0][j][64 + lane] = wp1;
  }
  __syncthreads();

  const bool hasNext = (h < 11);
  const bool isPubL  = (half == 0) && (j == 5);  // publishes head 5, consumes head 6
  const bool isPubH  = (half == 1) && (j == 0);  // publishes head 6, consumes head 5
  const int  flagPub = isPubL ? (b * 2 + 0) : (b * 2 + 1);
  const int  flagCon = isPubL ? (b * 2 + 1) : (b * 2 + 0);
  const bool isCon   = (sec == 0) && (isPubL || isPubH);
  bool dead = false;
  float thp = -3.0e38f;               // warm Michelot seed; k=0 -> full support (r8-verified)

  for (int k = 0; k < NIT; ++k) {
    const int p = k & 1;

    // ---------- matvec y = S * w_k: w broadcast by wave-uniform ds_read_b128 ----------
    {
      float a0 = 0.f, a1 = 0.f, a2 = 0.f, a3 = 0.f;
      const float* wrow = wbuf[p][j];
#pragma unroll 5
      for (int q = 0; q < 25; ++q) {
        float4 wq = *(const float4*)(wrow + q * 4);
        a0 = fmaf(wq.x, S[q * 4 + 0], a0);
        a1 = fmaf(wq.y, S[q * 4 + 1], a1);
        a2 = fmaf(wq.z, S[q * 4 + 2], a2);
        a3 = fmaf(wq.w, S[q * 4 + 3], a3);
      }
      if (lane < 50) ybuf[j][r] = (a0 + a2) + (a1 + a3);
    }

    // ---------- boundary prefetch AFTER matvec (r5) ----------
    float pf0 = 0.f, pf1 = 0.f;
    bool pfReady = false;
    if (isCon && k > 0) {
      if (__hip_atomic_load(&flags[flagCon], __ATOMIC_ACQUIRE, __HIP_MEMORY_SCOPE_AGENT) >= k) {
        const float* src = pbuf + ((size_t)flagCon * 2 + (k & 1)) * 100;
        pf0 = __hip_atomic_load(&src[lane], __ATOMIC_RELAXED, __HIP_MEMORY_SCOPE_AGENT);
        pf1 = val1 ? __hip_atomic_load(&src[64 + lane], __ATOMIC_RELAXED, __HIP_MEMORY_SCOPE_AGENT) : 0.f;
        pfReady = true;
      }
    }
    __syncthreads();

    // ---------- post phase: primary wave per head ----------
    if (sec == 0) {
      float y0 = ybuf[j][lane];
      float y1 = val1 ? ybuf[j][64 + lane] : 0.f;

      float ret = wred64(fmaf(mu0, w0, mu1 * w1));
      float s2  = wred64(fmaf(y0, w0, y1 * w1));
      float sigma = sqrtf(s2 + 1e-12f);
      float z     = KAPPA_ * sigma - ret - lim;
      float act   = (z > 0.f) ? 1.f : 0.f;
      float cY    = 2.f * GAMMA_ + act * (PEN_ * KAPPA_ / sigma);
      float cM    = -(1.f + act * PEN_);

      // neighbor w (iterate k exactly — Jacobi, matches reference)
      float wl0, wl1, wn0 = 0.f, wn1 = 0.f;
      if (j == 0) {
        if (half == 0 || k == 0) { wl0 = wp0; wl1 = wp1; }
        else {
          if (!pfReady) {
            if (!dead) {
              long guard = 0;
              while (__hip_atomic_load(&flags[flagCon], __ATOMIC_ACQUIRE, __HIP_MEMORY_SCOPE_AGENT) < k) {
                __builtin_amdgcn_s_sleep(1);
                if (++guard > (1L << 20)) { dead = true; break; }
              }
            }
            const float* src = pbuf + ((size_t)flagCon * 2 + (k & 1)) * 100;
            pf0 = __hip_atomic_load(&src[lane], __ATOMIC_RELAXED, __HIP_MEMORY_SCOPE_AGENT);
            pf1 = val1 ? __hip_atomic_load(&src[64 + lane], __ATOMIC_RELAXED, __HIP_MEMORY_SCOPE_AGENT) : 0.f;
          }
          wl0 = pf0; wl1 = pf1;
        }
      } else { wl0 = wbuf[p][j - 1][lane]; wl1 = val1 ? wbuf[p][j - 1][64 + lane] : 0.f; }
      if (hasNext) {
        if (j == 5) {  // half==0 boundary: next is head 6
          if (k == 0) { wn0 = wp0; wn1 = wp1; }
          else {
            if (!pfReady) {
              if (!dead) {
                long guard = 0;
                while (__hip_atomic_load(&flags[flagCon], __ATOMIC_ACQUIRE, __HIP_MEMORY_SCOPE_AGENT) < k) {
                  __builtin_amdgcn_s_sleep(1);
                  if (++guard > (1L << 20)) { dead = true; break; }
                }
              }
              const float* src = pbuf + ((size_t)flagCon * 2 + (k & 1)) * 100;
              pf0 = __hip_atomic_load(&src[lane], __ATOMIC_RELAXED, __HIP_MEMORY_SCOPE_AGENT);
              pf1 = val1 ? __hip_atomic_load(&src[64 + lane], __ATOMIC_RELAXED, __HIP_MEMORY_SCOPE_AGENT) : 0.f;
            }
            wn0 = pf0; wn1 = pf1;
          }
        } else { wn0 = wbuf[p][j + 1][lane]; wn1 = val1 ? wbuf[p][j + 1][64 + lane] : 0.f; }
      }

      float dw0 = w0 - wl0;
      float g0  = fmaf(cM, mu0, cY * y0) + CC_ * (dw0 * rsqrtf(fmaf(dw0, dw0, 1e-10f)));
      if (hasNext) { float dn0 = wn0 - w0; g0 -= CC_ * (dn0 * rsqrtf(fmaf(dn0, dn0, 1e-10f))); }
      float v0 = fmaf(-LR_, g0, w0);
      float v1 = 0.f;
      if (val1) {
        float dw1 = w1 - wl1;
        float g1  = fmaf(cM, mu1, cY * y1) + CC_ * (dw1 * rsqrtf(fmaf(dw1, dw1, 1e-10f)));
        if (hasNext) { float dn1 = wn1 - w1; g1 -= CC_ * (dn1 * rsqrtf(fmaf(dn1, dn1, 1e-10f))); }
        v1 = fmaf(-LR_, g1, w1);
      }

      // ---- Michelot projection, warm-started from previous theta (r8-verified).
      //      Exit (ns==Ssum && nc==Cnt) certifies Sum max(v-theta,0) == 1 exactly;
      //      pass-7 reset to full support restores the monotone guarantee. ----
      float a1m = val1 ? 1.f : 0.f;
      float na0 = (v0 > thp) ? 1.f : 0.f;
      float na1 = (val1 && (v1 > thp)) ? 1.f : 0.f;
      float Ssum = wred64(na0 * v0 + na1 * v1);
      float Cnt  = wred64(na0 + na1);
      if (Cnt < 0.5f) { Ssum = wred64(v0 + a1m * v1); Cnt = 100.f; }
      float theta = (Ssum - 1.f) / Cnt;
      for (int it = 0; it < 112; ++it) {
        na0 = (v0 > theta) ? 1.f : 0.f;
        na1 = (val1 && (v1 > theta)) ? 1.f : 0.f;
        float ns = wred64(na0 * v0 + na1 * v1);
        float nc = wred64(na0 + na1);
        if (nc == Cnt && ns == Ssum) break;
        if (it == 7) {  // warm-start may cycle: fall back to full support (monotone)
          ns = wred64(v0 + a1m * v1);
          nc = 100.f;
        }
        Ssum = ns; Cnt = nc;
        theta = (Ssum - 1.f) / Cnt;
      }
      thp = theta;
      w0 = fmaxf(v0 - theta, 0.f);
      w1 = val1 ? fmaxf(v1 - theta, 0.f) : 0.f;

      wbuf[1 - p][j][lane] = w0;
      if (val1) wbuf[1 - p][j][64 + lane] = w1;

      if (isPubL || isPubH) {
        float* dst = pbuf + ((size_t)flagPub * 2 + ((k + 1) & 1)) * 100;
        __hip_atomic_store(&dst[lane], w0, __ATOMIC_RELAXED, __HIP_MEMORY_SCOPE_AGENT);
        if (val1) __hip_atomic_store(&dst[64 + lane], w1, __ATOMIC_RELAXED, __HIP_MEMORY_SCOPE_AGENT);
        if (lane == 0)
          __hip_atomic_store(&flags[flagPub], k + 1, __ATOMIC_RELEASE, __HIP_MEMORY_SCOPE_AGENT);
      }
    }
    __syncthreads();
  }

  if (sec == 0) {
    float* o = out + (size_t)bh * 100;
    o[lane] = w0;
    if (val1) o[64 + lane] = w1;
  }
}

extern "C" void kernel_launch(void* const* d_in, const int* in_sizes, int n_in,
                              void* d_out, int out_size, void* d_ws, size_t ws_size,
                              hipStream_t stream) {
  const float* mu = (const float*)d_in[0];
  const float* L  = (const float*)d_in[1];
  const float* wp = (const float*)d_in[2];
  const float* cl = (const float*)d_in[3];
  float* pbuf  = (float*)d_ws;
  int*   flags = (int*)((char*)d_ws + PBUF_BYTES);
  hipMemsetAsync(flags, 0, FLAG_COUNT * sizeof(int), stream);
  hipLaunchKernelGGL(mpo_solver, dim3(256), dim3(768), 0, stream,
                     mu, L, wp, cl, (float*)d_out, pbuf, flags);
}

// Round 10
// 3015.449 us; speedup vs baseline: 3.1708x; 3.1708x over previous
//
#include <hip/hip_runtime.h>
#include <cstdint>
#include <cstddef>

// Problem constants (match reference)
#define NIT    500
#define GAMMA_ 5.0f
#define CC_    1e-3f
#define KAPPA_ 2.0627128075074256f
#define PEN_   100.0f
#define LR_    0.01f

// d_ws layout: pbuf [128 b][2 dir][2 parity][100] f32 = 204800 B, then flags [256] int
#define PBUF_BYTES (128*2*2*100*4)
#define FLAG_COUNT 256

__device__ __forceinline__ float rdlane(float v, int lane) {
  return __int_as_float(__builtin_amdgcn_readlane(__float_as_int(v), lane));
}

// Wave64 sum via DPP (row_shr 1,2,4,8 ; row_bcast15 ; row_bcast31), total in lane 63.
// Numerics verified r5/r7/r8/r9.
__device__ __forceinline__ float wred64(float x) {
  int t;
  t = __builtin_amdgcn_update_dpp(0, __float_as_int(x), 0x111, 0xf, 0xf, true); x += __int_as_float(t);
  t = __builtin_amdgcn_update_dpp(0, __float_as_int(x), 0x112, 0xf, 0xf, true); x += __int_as_float(t);
  t = __builtin_amdgcn_update_dpp(0, __float_as_int(x), 0x114, 0xf, 0xf, true); x += __int_as_float(t);
  t = __builtin_amdgcn_update_dpp(0, __float_as_int(x), 0x118, 0xf, 0xf, true); x += __int_as_float(t);
  t = __builtin_amdgcn_update_dpp(0, __float_as_int(x), 0x142, 0xa, 0xf, true); x += __int_as_float(t);
  t = __builtin_amdgcn_update_dpp(0, __float_as_int(x), 0x143, 0xc, 0xf, true); x += __int_as_float(t);
  return rdlane(x, 63);
}

// r5 skeleton (256 WGs, one per (b,half), 6 heads x 2 waves, 2 barriers/iter).
// Matvec w-broadcast via FULLY-UNROLLED wave-uniform ds_read_b128:
//   - S indexed ONLY by compile-time constants -> stays in AGPRs
//     (r9 proved: any runtime index on S -> scratch spill -> 19.6 GB FETCH, 3x slower)
//   - no v_readlane -> no SGPR-write hazards on the chain (~130 instr vs ~210)
// A-wave keeps its own y rows (0-49) in registers; only B writes ybuf.
// Warm-started Michelot (r8/r9-verified, absmax identical).
__global__ __launch_bounds__(768, 1) void mpo_solver(
    const float* __restrict__ mu, const float* __restrict__ L,
    const float* __restrict__ wprev, const float* __restrict__ climit,
    float* __restrict__ out, float* __restrict__ pbuf, int* __restrict__ flags)
{
  const int tid  = threadIdx.x;
  const int lane = tid & 63;
  const int wave = __builtin_amdgcn_readfirstlane(tid >> 6);  // 0..11
  const int j    = wave >> 1;       // local head 0..5
  const int sec  = wave & 1;        // 0 = rows 0-49 + post, 1 = rows 50-99
  const int bid  = blockIdx.x;
  const int b    = bid & 127;
  const int half = bid >> 7;        // 0: heads 0-5, 1: heads 6-11
  const int h    = half * 6 + j;    // global head
  const int bh   = b * 12 + h;

  __shared__ float wbuf[2][6][100];   // double-buffered w per head
  __shared__ float ybuf[6][100];      // y rows 50-99 per head (B-wave's half)

  const float* Lb = L + (size_t)bh * 10000;

  // ---------- Phase 0: SYRK. Lane owns row r of S = L L^T (fp32, in registers). ----------
  float S[100];
#pragma unroll
  for (int c = 0; c < 100; ++c) S[c] = 0.f;
  const int r = sec * 50 + lane;      // valid row iff lane < 50
  if (lane < 50) {
#pragma unroll 1
    for (int mc = 0; mc < 25; ++mc) {
      float4 lr = *(const float4*)(Lb + r * 100 + mc * 4);
#pragma unroll
      for (int c = 0; c < 100; ++c) {
        const float* Lc = Lb + c * 100 + mc * 4;   // wave-uniform address -> scalar loads
        S[c] = fmaf(lr.x, Lc[0], fmaf(lr.y, Lc[1], fmaf(lr.z, Lc[2], fmaf(lr.w, Lc[3], S[c]))));
      }
    }
  }

  const bool val1 = (lane < 36);
  float mu0 = mu[(size_t)bh * 100 + lane];
  float mu1 = val1 ? mu[(size_t)bh * 100 + 64 + lane] : 0.f;
  float wp0 = wprev[b * 100 + lane];
  float wp1 = val1 ? wprev[b * 100 + 64 + lane] : 0.f;
  float lim = climit[b];

  float w0 = wp0, w1 = wp1;           // post wave's iterate (n = lane, 64+lane)

  if (sec == 0) {
    wbuf[0][j][lane] = wp0;
    if (val1) wbuf[0][j][64 + lane] = wp1;
  }
  __syncthreads();

  const bool hasNext = (h < 11);
  const bool isPubL  = (half == 0) && (j == 5);  // publishes head 5, consumes head 6
  const bool isPubH  = (half == 1) && (j == 0);  // publishes head 6, consumes head 5
  const int  flagPub = isPubL ? (b * 2 + 0) : (b * 2 + 1);
  const int  flagCon = isPubL ? (b * 2 + 1) : (b * 2 + 0);
  const bool isCon   = (sec == 0) && (isPubL || isPubH);
  bool dead = false;
  float thp = -3.0e38f;               // warm Michelot seed; k=0 -> full support

  for (int k = 0; k < NIT; ++k) {
    const int p = k & 1;

    // ---------- matvec y = S * w_k: w broadcast by wave-uniform ds_read_b128,
    //            FULL unroll so S[] indices are compile-time constants ----------
    float yloc;
    {
      float a0 = 0.f, a1 = 0.f, a2 = 0.f, a3 = 0.f;
      const float* wrow = wbuf[p][j];
#pragma unroll
      for (int q = 0; q < 25; ++q) {
        float4 wq = *(const float4*)(wrow + q * 4);
        a0 = fmaf(wq.x, S[q * 4 + 0], a0);
        a1 = fmaf(wq.y, S[q * 4 + 1], a1);
        a2 = fmaf(wq.z, S[q * 4 + 2], a2);
        a3 = fmaf(wq.w, S[q * 4 + 3], a3);
      }
      yloc = (a0 + a2) + (a1 + a3);
      if (sec == 1 && lane < 50) ybuf[j][50 + lane] = yloc;  // only B publishes its half
    }

    // ---------- boundary prefetch AFTER matvec (r5) ----------
    float pf0 = 0.f, pf1 = 0.f;
    bool pfReady = false;
    if (isCon && k > 0) {
      if (__hip_atomic_load(&flags[flagCon], __ATOMIC_ACQUIRE, __HIP_MEMORY_SCOPE_AGENT) >= k) {
        const float* src = pbuf + ((size_t)flagCon * 2 + (k & 1)) * 100;
        pf0 = __hip_atomic_load(&src[lane], __ATOMIC_RELAXED, __HIP_MEMORY_SCOPE_AGENT);
        pf1 = val1 ? __hip_atomic_load(&src[64 + lane], __ATOMIC_RELAXED, __HIP_MEMORY_SCOPE_AGENT) : 0.f;
        pfReady = true;
      }
    }
    __syncthreads();

    // ---------- post phase: primary wave per head ----------
    if (sec == 0) {
      // y[lane]: rows 0-49 are THIS wave's registers; rows 50-99 from B via ybuf
      float y0 = (lane < 50) ? yloc : ybuf[j][lane];
      float y1 = val1 ? ybuf[j][64 + lane] : 0.f;

      float ret = wred64(fmaf(mu0, w0, mu1 * w1));
      float s2  = wred64(fmaf(y0, w0, y1 * w1));
      float sigma = sqrtf(s2 + 1e-12f);
      float z     = KAPPA_ * sigma - ret - lim;
      float act   = (z > 0.f) ? 1.f : 0.f;
      float cY    = 2.f * GAMMA_ + act * (PEN_ * KAPPA_ / sigma);
      float cM    = -(1.f + act * PEN_);

      // neighbor w (iterate k exactly — Jacobi, matches reference)
      float wl0, wl1, wn0 = 0.f, wn1 = 0.f;
      if (j == 0) {
        if (half == 0 || k == 0) { wl0 = wp0; wl1 = wp1; }
        else {
          if (!pfReady) {
            if (!dead) {
              long guard = 0;
              while (__hip_atomic_load(&flags[flagCon], __ATOMIC_ACQUIRE, __HIP_MEMORY_SCOPE_AGENT) < k) {
                __builtin_amdgcn_s_sleep(1);
                if (++guard > (1L << 20)) { dead = true; break; }
              }
            }
            const float* src = pbuf + ((size_t)flagCon * 2 + (k & 1)) * 100;
            pf0 = __hip_atomic_load(&src[lane], __ATOMIC_RELAXED, __HIP_MEMORY_SCOPE_AGENT);
            pf1 = val1 ? __hip_atomic_load(&src[64 + lane], __ATOMIC_RELAXED, __HIP_MEMORY_SCOPE_AGENT) : 0.f;
          }
          wl0 = pf0; wl1 = pf1;
        }
      } else { wl0 = wbuf[p][j - 1][lane]; wl1 = val1 ? wbuf[p][j - 1][64 + lane] : 0.f; }
      if (hasNext) {
        if (j == 5) {  // half==0 boundary: next is head 6
          if (k == 0) { wn0 = wp0; wn1 = wp1; }
          else {
            if (!pfReady) {
              if (!dead) {
                long guard = 0;
                while (__hip_atomic_load(&flags[flagCon], __ATOMIC_ACQUIRE, __HIP_MEMORY_SCOPE_AGENT) < k) {
                  __builtin_amdgcn_s_sleep(1);
                  if (++guard > (1L << 20)) { dead = true; break; }
                }
              }
              const float* src = pbuf + ((size_t)flagCon * 2 + (k & 1)) * 100;
              pf0 = __hip_atomic_load(&src[lane], __ATOMIC_RELAXED, __HIP_MEMORY_SCOPE_AGENT);
              pf1 = val1 ? __hip_atomic_load(&src[64 + lane], __ATOMIC_RELAXED, __HIP_MEMORY_SCOPE_AGENT) : 0.f;
            }
            wn0 = pf0; wn1 = pf1;
          }
        } else { wn0 = wbuf[p][j + 1][lane]; wn1 = val1 ? wbuf[p][j + 1][64 + lane] : 0.f; }
      }

      float dw0 = w0 - wl0;
      float g0  = fmaf(cM, mu0, cY * y0) + CC_ * (dw0 * rsqrtf(fmaf(dw0, dw0, 1e-10f)));
      if (hasNext) { float dn0 = wn0 - w0; g0 -= CC_ * (dn0 * rsqrtf(fmaf(dn0, dn0, 1e-10f))); }
      float v0 = fmaf(-LR_, g0, w0);
      float v1 = 0.f;
      if (val1) {
        float dw1 = w1 - wl1;
        float g1  = fmaf(cM, mu1, cY * y1) + CC_ * (dw1 * rsqrtf(fmaf(dw1, dw1, 1e-10f)));
        if (hasNext) { float dn1 = wn1 - w1; g1 -= CC_ * (dn1 * rsqrtf(fmaf(dn1, dn1, 1e-10f))); }
        v1 = fmaf(-LR_, g1, w1);
      }

      // ---- Michelot projection, warm-started from previous theta (r8/r9-verified).
      //      Exit (ns==Ssum && nc==Cnt) certifies Sum max(v-theta,0) == 1 exactly;
      //      pass-7 reset to full support restores the monotone guarantee. ----
      float a1m = val1 ? 1.f : 0.f;
      float na0 = (v0 > thp) ? 1.f : 0.f;
      float na1 = (val1 && (v1 > thp)) ? 1.f : 0.f;
      float Ssum = wred64(na0 * v0 + na1 * v1);
      float Cnt  = wred64(na0 + na1);
      if (Cnt < 0.5f) { Ssum = wred64(v0 + a1m * v1); Cnt = 100.f; }
      float theta = (Ssum - 1.f) / Cnt;
      for (int it = 0; it < 112; ++it) {
        na0 = (v0 > theta) ? 1.f : 0.f;
        na1 = (val1 && (v1 > theta)) ? 1.f : 0.f;
        float ns = wred64(na0 * v0 + na1 * v1);
        float nc = wred64(na0 + na1);
        if (nc == Cnt && ns == Ssum) break;
        if (it == 7) {  // warm-start may cycle: fall back to full support (monotone)
          ns = wred64(v0 + a1m * v1);
          nc = 100.f;
        }
        Ssum = ns; Cnt = nc;
        theta = (Ssum - 1.f) / Cnt;
      }
      thp = theta;
      w0 = fmaxf(v0 - theta, 0.f);
      w1 = val1 ? fmaxf(v1 - theta, 0.f) : 0.f;

      wbuf[1 - p][j][lane] = w0;
      if (val1) wbuf[1 - p][j][64 + lane] = w1;

      if (isPubL || isPubH) {
        float* dst = pbuf + ((size_t)flagPub * 2 + ((k + 1) & 1)) * 100;
        __hip_atomic_store(&dst[lane], w0, __ATOMIC_RELAXED, __HIP_MEMORY_SCOPE_AGENT);
        if (val1) __hip_atomic_store(&dst[64 + lane], w1, __ATOMIC_RELAXED, __HIP_MEMORY_SCOPE_AGENT);
        if (lane == 0)
          __hip_atomic_store(&flags[flagPub], k + 1, __ATOMIC_RELEASE, __HIP_MEMORY_SCOPE_AGENT);
      }
    }
    __syncthreads();
  }

  if (sec == 0) {
    float* o = out + (size_t)bh * 100;
    o[lane] = w0;
    if (val1) o[64 + lane] = w1;
  }
}

extern "C" void kernel_launch(void* const* d_in, const int* in_sizes, int n_in,
                              void* d_out, int out_size, void* d_ws, size_t ws_size,
                              hipStream_t stream) {
  const float* mu = (const float*)d_in[0];
  const float* L  = (const float*)d_in[1];
  const float* wp = (const float*)d_in[2];
  const float* cl = (const float*)d_in[3];
  float* pbuf  = (float*)d_ws;
  int*   flags = (int*)((char*)d_ws + PBUF_BYTES);
  hipMemsetAsync(flags, 0, FLAG_COUNT * sizeof(int), stream);
  hipLaunchKernelGGL(mpo_solver, dim3(256), dim3(768), 0, stream,
                     mu, L, wp, cl, (float*)d_out, pbuf, flags);
}

// Round 11
// 1897.093 us; speedup vs baseline: 5.0400x; 1.5895x over previous
//
#include <hip/hip_runtime.h>
#include <cstdint>
#include <cstddef>

// Problem constants (match reference)
#define NIT    500
#define GAMMA_ 5.0f
#define CC_    1e-3f
#define KAPPA_ 2.0627128075074256f
#define PEN_   100.0f
#define LR_    0.01f

// d_ws layout: pbuf [128 b][2 dir][2 parity][100] f32 = 204800 B, then flags [256] int
#define PBUF_BYTES (128*2*2*100*4)
#define FLAG_COUNT 256

// Cross-WG primitives: system-scope RELAXED RMWs only. RMWs execute at the
// coherence point (no stale L2 reads), and relaxed ordering emits NO cache-wide
// maintenance ops (agent-scope acquire/release on multi-XCD gfx9 emits L2
// invalidate/writeback per op — the r1..r10 fixed ~6us/iter floor).
#define VMFENCE() asm volatile("s_waitcnt vmcnt(0)" ::: "memory")
__device__ __forceinline__ float sysLoadF(float* p) {
  return __hip_atomic_fetch_add(p, 0.0f, __ATOMIC_RELAXED, __HIP_MEMORY_SCOPE_SYSTEM);
}
__device__ __forceinline__ void sysStoreF(float* p, float v) {
  (void)__hip_atomic_exchange(p, v, __ATOMIC_RELAXED, __HIP_MEMORY_SCOPE_SYSTEM);
}
__device__ __forceinline__ int sysLoadI(int* p) {
  return __hip_atomic_fetch_add(p, 0, __ATOMIC_RELAXED, __HIP_MEMORY_SCOPE_SYSTEM);
}
__device__ __forceinline__ void sysStoreI(int* p, int v) {
  (void)__hip_atomic_exchange(p, v, __ATOMIC_RELAXED, __HIP_MEMORY_SCOPE_SYSTEM);
}

__device__ __forceinline__ float rdlane(float v, int lane) {
  return __int_as_float(__builtin_amdgcn_readlane(__float_as_int(v), lane));
}

// Wave64 sum via DPP (row_shr 1,2,4,8 ; row_bcast15 ; row_bcast31), total in lane 63.
// Numerics verified r5/r7/r8/r9/r10.
__device__ __forceinline__ float wred64(float x) {
  int t;
  t = __builtin_amdgcn_update_dpp(0, __float_as_int(x), 0x111, 0xf, 0xf, true); x += __int_as_float(t);
  t = __builtin_amdgcn_update_dpp(0, __float_as_int(x), 0x112, 0xf, 0xf, true); x += __int_as_float(t);
  t = __builtin_amdgcn_update_dpp(0, __float_as_int(x), 0x114, 0xf, 0xf, true); x += __int_as_float(t);
  t = __builtin_amdgcn_update_dpp(0, __float_as_int(x), 0x118, 0xf, 0xf, true); x += __int_as_float(t);
  t = __builtin_amdgcn_update_dpp(0, __float_as_int(x), 0x142, 0xa, 0xf, true); x += __int_as_float(t);
  t = __builtin_amdgcn_update_dpp(0, __float_as_int(x), 0x143, 0xc, 0xf, true); x += __int_as_float(t);
  return rdlane(x, 63);
}

// r10 kernel verbatim except the cross-WG handshake primitives (see above).
// S indexed ONLY by compile-time constants -> stays in AGPRs (r9: runtime index
// -> scratch spill -> 19.6 GB FETCH). Matvec via wave-uniform ds_read_b128.
__global__ __launch_bounds__(768, 1) void mpo_solver(
    const float* __restrict__ mu, const float* __restrict__ L,
    const float* __restrict__ wprev, const float* __restrict__ climit,
    float* __restrict__ out, float* __restrict__ pbuf, int* __restrict__ flags)
{
  const int tid  = threadIdx.x;
  const int lane = tid & 63;
  const int wave = __builtin_amdgcn_readfirstlane(tid >> 6);  // 0..11
  const int j    = wave >> 1;       // local head 0..5
  const int sec  = wave & 1;        // 0 = rows 0-49 + post, 1 = rows 50-99
  const int bid  = blockIdx.x;
  const int b    = bid & 127;
  const int half = bid >> 7;        // 0: heads 0-5, 1: heads 6-11
  const int h    = half * 6 + j;    // global head
  const int bh   = b * 12 + h;

  __shared__ float wbuf[2][6][100];   // double-buffered w per head
  __shared__ float ybuf[6][100];      // y rows 50-99 per head (B-wave's half)

  const float* Lb = L + (size_t)bh * 10000;

  // ---------- Phase 0: SYRK. Lane owns row r of S = L L^T (fp32, in registers). ----------
  float S[100];
#pragma unroll
  for (int c = 0; c < 100; ++c) S[c] = 0.f;
  const int r = sec * 50 + lane;      // valid row iff lane < 50
  if (lane < 50) {
#pragma unroll 1
    for (int mc = 0; mc < 25; ++mc) {
      float4 lr = *(const float4*)(Lb + r * 100 + mc * 4);
#pragma unroll
      for (int c = 0; c < 100; ++c) {
        const float* Lc = Lb + c * 100 + mc * 4;   // wave-uniform address -> scalar loads
        S[c] = fmaf(lr.x, Lc[0], fmaf(lr.y, Lc[1], fmaf(lr.z, Lc[2], fmaf(lr.w, Lc[3], S[c]))));
      }
    }
  }

  const bool val1 = (lane < 36);
  float mu0 = mu[(size_t)bh * 100 + lane];
  float mu1 = val1 ? mu[(size_t)bh * 100 + 64 + lane] : 0.f;
  float wp0 = wprev[b * 100 + lane];
  float wp1 = val1 ? wprev[b * 100 + 64 + lane] : 0.f;
  float lim = climit[b];

  float w0 = wp0, w1 = wp1;           // post wave's iterate (n = lane, 64+lane)

  if (sec == 0) {
    wbuf[0][j][lane] = wp0;
    if (val1) wbuf[0][j][64 + lane] = wp1;
  }
  __syncthreads();

  const bool hasNext = (h < 11);
  const bool isPubL  = (half == 0) && (j == 5);  // publishes head 5, consumes head 6
  const bool isPubH  = (half == 1) && (j == 0);  // publishes head 6, consumes head 5
  const int  flagPub = isPubL ? (b * 2 + 0) : (b * 2 + 1);
  const int  flagCon = isPubL ? (b * 2 + 1) : (b * 2 + 0);
  const bool isCon   = (sec == 0) && (isPubL || isPubH);
  bool dead = false;
  float thp = -3.0e38f;               // warm Michelot seed; k=0 -> full support

  for (int k = 0; k < NIT; ++k) {
    const int p = k & 1;

    // ---------- matvec y = S * w_k: w broadcast by wave-uniform ds_read_b128,
    //            FULL unroll so S[] indices are compile-time constants ----------
    float yloc;
    {
      float a0 = 0.f, a1 = 0.f, a2 = 0.f, a3 = 0.f;
      const float* wrow = wbuf[p][j];
#pragma unroll
      for (int q = 0; q < 25; ++q) {
        float4 wq = *(const float4*)(wrow + q * 4);
        a0 = fmaf(wq.x, S[q * 4 + 0], a0);
        a1 = fmaf(wq.y, S[q * 4 + 1], a1);
        a2 = fmaf(wq.z, S[q * 4 + 2], a2);
        a3 = fmaf(wq.w, S[q * 4 + 3], a3);
      }
      yloc = (a0 + a2) + (a1 + a3);
      if (sec == 1 && lane < 50) ybuf[j][50 + lane] = yloc;  // only B publishes its half
    }

    // ---------- boundary prefetch AFTER matvec (system-relaxed RMWs) ----------
    float pf0 = 0.f, pf1 = 0.f;
    bool pfReady = false;
    if (isCon && k > 0) {
      if (sysLoadI(&flags[flagCon]) >= k) {
        float* src = pbuf + ((size_t)flagCon * 2 + (k & 1)) * 100;
        pf0 = sysLoadF(&src[lane]);
        pf1 = val1 ? sysLoadF(&src[64 + lane]) : 0.f;
        pfReady = true;
      }
    }
    __syncthreads();

    // ---------- post phase: primary wave per head ----------
    if (sec == 0) {
      // y[lane]: rows 0-49 are THIS wave's registers; rows 50-99 from B via ybuf
      float y0 = (lane < 50) ? yloc : ybuf[j][lane];
      float y1 = val1 ? ybuf[j][64 + lane] : 0.f;

      float ret = wred64(fmaf(mu0, w0, mu1 * w1));
      float s2  = wred64(fmaf(y0, w0, y1 * w1));
      float sigma = sqrtf(s2 + 1e-12f);
      float z     = KAPPA_ * sigma - ret - lim;
      float act   = (z > 0.f) ? 1.f : 0.f;
      float cY    = 2.f * GAMMA_ + act * (PEN_ * KAPPA_ / sigma);
      float cM    = -(1.f + act * PEN_);

      // neighbor w (iterate k exactly — Jacobi, matches reference)
      float wl0, wl1, wn0 = 0.f, wn1 = 0.f;
      if (j == 0) {
        if (half == 0 || k == 0) { wl0 = wp0; wl1 = wp1; }
        else {
          if (!pfReady) {
            if (!dead) {
              long guard = 0;
              while (sysLoadI(&flags[flagCon]) < k) {
                __builtin_amdgcn_s_sleep(2);
                if (++guard > (1L << 17)) { dead = true; break; }
              }
            }
            float* src = pbuf + ((size_t)flagCon * 2 + (k & 1)) * 100;
            pf0 = sysLoadF(&src[lane]);
            pf1 = val1 ? sysLoadF(&src[64 + lane]) : 0.f;
          }
          wl0 = pf0; wl1 = pf1;
        }
      } else { wl0 = wbuf[p][j - 1][lane]; wl1 = val1 ? wbuf[p][j - 1][64 + lane] : 0.f; }
      if (hasNext) {
        if (j == 5) {  // half==0 boundary: next is head 6
          if (k == 0) { wn0 = wp0; wn1 = wp1; }
          else {
            if (!pfReady) {
              if (!dead) {
                long guard = 0;
                while (sysLoadI(&flags[flagCon]) < k) {
                  __builtin_amdgcn_s_sleep(2);
                  if (++guard > (1L << 17)) { dead = true; break; }
                }
              }
              float* src = pbuf + ((size_t)flagCon * 2 + (k & 1)) * 100;
              pf0 = sysLoadF(&src[lane]);
              pf1 = val1 ? sysLoadF(&src[64 + lane]) : 0.f;
            }
            wn0 = pf0; wn1 = pf1;
          }
        } else { wn0 = wbuf[p][j + 1][lane]; wn1 = val1 ? wbuf[p][j + 1][64 + lane] : 0.f; }
      }

      float dw0 = w0 - wl0;
      float g0  = fmaf(cM, mu0, cY * y0) + CC_ * (dw0 * rsqrtf(fmaf(dw0, dw0, 1e-10f)));
      if (hasNext) { float dn0 = wn0 - w0; g0 -= CC_ * (dn0 * rsqrtf(fmaf(dn0, dn0, 1e-10f))); }
      float v0 = fmaf(-LR_, g0, w0);
      float v1 = 0.f;
      if (val1) {
        float dw1 = w1 - wl1;
        float g1  = fmaf(cM, mu1, cY * y1) + CC_ * (dw1 * rsqrtf(fmaf(dw1, dw1, 1e-10f)));
        if (hasNext) { float dn1 = wn1 - w1; g1 -= CC_ * (dn1 * rsqrtf(fmaf(dn1, dn1, 1e-10f))); }
        v1 = fmaf(-LR_, g1, w1);
      }

      // ---- Michelot projection, warm-started from previous theta (r8/r9/r10-verified).
      //      Exit (ns==Ssum && nc==Cnt) certifies Sum max(v-theta,0) == 1 exactly;
      //      pass-7 reset to full support restores the monotone guarantee. ----
      float a1m = val1 ? 1.f : 0.f;
      float na0 = (v0 > thp) ? 1.f : 0.f;
      float na1 = (val1 && (v1 > thp)) ? 1.f : 0.f;
      float Ssum = wred64(na0 * v0 + na1 * v1);
      float Cnt  = wred64(na0 + na1);
      if (Cnt < 0.5f) { Ssum = wred64(v0 + a1m * v1); Cnt = 100.f; }
      float theta = (Ssum - 1.f) / Cnt;
      for (int it = 0; it < 112; ++it) {
        na0 = (v0 > theta) ? 1.f : 0.f;
        na1 = (val1 && (v1 > theta)) ? 1.f : 0.f;
        float ns = wred64(na0 * v0 + na1 * v1);
        float nc = wred64(na0 + na1);
        if (nc == Cnt && ns == Ssum) break;
        if (it == 7) {  // warm-start may cycle: fall back to full support (monotone)
          ns = wred64(v0 + a1m * v1);
          nc = 100.f;
        }
        Ssum = ns; Cnt = nc;
        theta = (Ssum - 1.f) / Cnt;
      }
      thp = theta;
      w0 = fmaxf(v0 - theta, 0.f);
      w1 = val1 ? fmaxf(v1 - theta, 0.f) : 0.f;

      wbuf[1 - p][j][lane] = w0;
      if (val1) wbuf[1 - p][j][64 + lane] = w1;

      if (isPubL || isPubH) {
        float* dst = pbuf + ((size_t)flagPub * 2 + ((k + 1) & 1)) * 100;
        sysStoreF(&dst[lane], w0);
        if (val1) sysStoreF(&dst[64 + lane], w1);
        if (lane == 0) {
          VMFENCE();   // data RMWs reached the coherence point before flag store issues
          sysStoreI(&flags[flagPub], k + 1);
        }
      }
    }
    __syncthreads();
  }

  if (sec == 0) {
    float* o = out + (size_t)bh * 100;
    o[lane] = w0;
    if (val1) o[64 + lane] = w1;
  }
}

extern "C" void kernel_launch(void* const* d_in, const int* in_sizes, int n_in,
                              void* d_out, int out_size, void* d_ws, size_t ws_size,
                              hipStream_t stream) {
  const float* mu = (const float*)d_in[0];
  const float* L  = (const float*)d_in[1];
  const float* wp = (const float*)d_in[2];
  const float* cl = (const float*)d_in[3];
  float* pbuf  = (float*)d_ws;
  int*   flags = (int*)((char*)d_ws + PBUF_BYTES);
  hipMemsetAsync(flags, 0, FLAG_COUNT * sizeof(int), stream);
  hipLaunchKernelGGL(mpo_solver, dim3(256), dim3(768), 0, stream,
                     mu, L, wp, cl, (float*)d_out, pbuf, flags);
}